// Round 4
// baseline (122.453 us; speedup 1.0000x reference)
//
#include <hip/hip_runtime.h>
#include <math.h>

#define EPS 1e-6f
constexpr int B    = 64;
constexpr int F    = 2;
constexpr int NC   = 10;
constexpr int ND   = 4;
constexpr int CHW  = 64 * 16 * 16;   // 16384
constexpr int FCHW = F * CHW;        // 32768

__device__ __forceinline__ float log_sigmoid(float x) {
    // jax.nn.log_sigmoid: -log1p(exp(-x)), stabilized
    return fminf(x, 0.0f) - log1pf(expf(-fabsf(x)));
}

// Single fused kernel, NO grid sync needed:
// grid 256 blocks x 256 threads; s-chunk of 64 per block (s = blk*64 + lane).
// All 4 waves of a block redundantly compute phase A (means for all NC at
// their s) entirely in registers; then wave w computes x_out for its
// b-quarter using those register-resident means. Loss is linear in the
// per-(nc,nd) norm partials, so wave 0 of each block atomicAdds its
// coef-weighted partial straight into out[B*CHW+nd] (out is zeroed by the
// harness before each launch).
__global__ void k_fused_all(const float* __restrict__ xLE, const int* __restrict__ labels,
                            const float* __restrict__ w1, const float* __restrict__ miu,
                            const float* __restrict__ tao, const float* __restrict__ sigmas,
                            const float* __restrict__ Xw, const float* __restrict__ XLEs,
                            const float* __restrict__ weight,
                            float* __restrict__ out /* [B*CHW] xout, then [ND] loss */) {
    const int tid  = threadIdx.x;
    const int lane = tid & 63;
    const int wv   = tid >> 6;               // 0..3
    const int s    = blockIdx.x * 64 + lane; // [0, CHW)

    // ---- ballot masks: bit b set iff labels[b] == nc (B == 64 == wave size)
    int lab_l = labels[lane];
    unsigned long long mask[NC];
#pragma unroll
    for (int nc = 0; nc < NC; ++nc) mask[nc] = __ballot(lab_l == nc);

    // ---- miu-dependent values: computed ONCE per s (not per nc)
    float m0r[ND], lsm0[ND], lsm1[ND], lsme[ND];
#pragma unroll
    for (int nd = 0; nd < ND; ++nd) {
        float m0 = miu[nd * FCHW + s];
        float m1 = miu[nd * FCHW + CHW + s];
        m0r[nd]  = m0;
        lsm0[nd] = log_sigmoid(m0);
        lsm1[nd] = log_sigmoid(m1);
        lsme[nd] = log_sigmoid(m1 + EPS);
    }

    float wn[ND], tao2[ND];
    {
        float s1 = 0.0f;
#pragma unroll
        for (int nd = 0; nd < ND; ++nd) { float t = w1[nd]; wn[nd] = t * t; s1 += t * t; }
        float inv_s1 = 1.0f / s1;
#pragma unroll
        for (int nd = 0; nd < ND; ++nd) {
            wn[nd] *= inv_s1;                 // w1n == w2n in the reference
            float tv = tao[nd];
            tao2[nd] = tv * tv;
        }
    }

    // ---- phase A: per-nc means + coef-weighted loss partials (registers only)
    float mt_r[NC], lnm_r[NC];
    float closs[ND] = {0.0f, 0.0f, 0.0f, 0.0f};
#pragma unroll
    for (int nc = 0; nc < NC; ++nc) {
        float bin0 = XLEs[nc * FCHW + s];
        float bin1 = XLEs[nc * FCHW + CHW + s];
        unsigned long long mm = mask[nc];
        int cint = __popcll(mm);
        while (mm) {
            int b = __builtin_ctzll(mm);      // wave-uniform
            mm &= mm - 1;
            bin0 += xLE[b * FCHW + s];        // coalesced
            bin1 += xLE[b * FCHW + CHW + s];
        }
        float cnt = Xw[nc] + (float)cint;
        float inv_cnt = 1.0f / cnt;
        float xb0 = bin0 * inv_cnt;
        float xb1 = bin1 * inv_cnt;
        float ls0  = log_sigmoid(xb0);
        float ls1v = log_sigmoid(xb1);
        float ls1e = log_sigmoid(xb1 + EPS);
        float sg   = sigmas[nc];
        float sig2 = sg * sg;

        float theta = 0.0f, magm = 0.0f;
#pragma unroll
        for (int nd = 0; nd < ND; ++nd) {
            float d0 = ls0  - lsm0[nd];
            float d1 = ls1v - lsm1[nd];
            float ps = d0 * d0 + d1 * d1;
            float denom = 1.0f / (sig2 + tao2[nd]);
            float rt = tao2[nd] * denom;
            float rs = sig2 * denom;
            theta += (xb1 * rt + m0r[nd] * rs) * wn[nd];
            magm  += expf((rt * ls1e + rs * lsme[nd]) * wn[nd]);
            // term1*sig2 = sig2*denom^2 * sig2 ; psum contribution to loss[nd]
            closs[nd] += (sig2 * denom) * (sig2 * denom) * ps;
        }
        mt_r[nc]  = theta;
        lnm_r[nc] = logf(magm + EPS);
    }

    // ---- loss partials: wave 0 only (waves are redundant copies)
    if (wv == 0) {
#pragma unroll
        for (int nd = 0; nd < ND; ++nd) {
            float v = closs[nd];
            for (int off = 32; off > 0; off >>= 1)
                v += __shfl_down(v, off, 64);
            closs[nd] = v;
        }
        if (lane == 0) {
#pragma unroll
            for (int nd = 0; nd < ND; ++nd)
                atomicAdd(&out[B * CHW + nd], closs[nd] * (1.0f / (float)NC));
        }
        // constant term (independent of s): block 0 only, lane = nd
        if (blockIdx.x == 0 && lane < ND) {
            int nd = lane;
            float t2v = tao2[nd];
            float tao4 = t2v * t2v;
            float acc = 0.0f;
            for (int nc = 0; nc < NC; ++nc) {
                float sg   = sigmas[nc];
                float sig2 = sg * sg;
                float cnt  = Xw[nc] + (float)__popcll(mask[nc]);
                float denom = 1.0f / (sig2 + t2v);
                float t1 = sig2 * denom * denom;
                float t3 = 2.0f * (float)CHW * (tao4 - sig2 * sig2) / cnt;
                acc += t1 * t3;
            }
            atomicAdd(&out[B * CHW + nd], acc * (1.0f / (float)NC));
        }
    }

    // ---- phase B: x_out for this wave's b-quarter, means from registers
    float wv0 = weight[0], wv1 = weight[1];
    float w0 = wv0 * wv0, w1s = wv1 * wv1;
    const int b0 = wv * (B / 4);
    for (int bi = 0; bi < B / 4; ++bi) {
        int b = b0 + bi;
        float x0 = xLE[b * FCHW + s];          // L2-hit (read in phase A)
        float x1 = xLE[b * FCHW + CHW + s];
        float lnx = logf(x1);
        float best = INFINITY;
#pragma unroll
        for (int c = 0; c < NC; ++c) {
            float d = w0 * fabsf(x0 - mt_r[c]) + w1s * fabsf(lnx - lnm_r[c]);
            best = fminf(best, d);
        }
        out[b * CHW + s] = best;               // coalesced (64 consecutive)
    }
}

extern "C" void kernel_launch(void* const* d_in, const int* in_sizes, int n_in,
                              void* d_out, int out_size, void* d_ws, size_t ws_size,
                              hipStream_t stream) {
    const float* xLE    = (const float*)d_in[0];
    const int*   labels = (const int*)  d_in[1];
    const float* w1     = (const float*)d_in[2];
    // d_in[3] (w2) is unused: the reference computes w2n from w1.
    const float* miu    = (const float*)d_in[4];
    const float* tao    = (const float*)d_in[5];
    const float* weight = (const float*)d_in[6];
    const float* sigmas = (const float*)d_in[7];
    const float* XLEs   = (const float*)d_in[8];
    const float* Xw     = (const float*)d_in[9];

    float* out = (float*)d_out;   // x_out [B*CHW] then loss [ND]; pre-zeroed by harness

    k_fused_all<<<CHW / 64, 256, 0, stream>>>(
        xLE, labels, w1, miu, tao, sigmas, Xw, XLEs, weight, out);
}

// Round 5
// 90.941 us; speedup vs baseline: 1.3465x; 1.3465x over previous
//
#include <hip/hip_runtime.h>
#include <math.h>

#define EPS 1e-6f
constexpr int B    = 64;
constexpr int F    = 2;
constexpr int NC   = 10;
constexpr int ND   = 4;
constexpr int CHW  = 64 * 16 * 16;   // 16384
constexpr int FCHW = F * CHW;        // 32768
constexpr int SS   = 32;             // s-values per block
constexpr int NG   = 8;              // thread groups per block (256/SS)

__device__ __forceinline__ float log_sigmoid(float x) {
    // jax.nn.log_sigmoid: -log1p(exp(-x)), stabilized
    return fminf(x, 0.0f) - log1pf(expf(-fabsf(x)));
}

// Single fused kernel, no grid sync, occupancy-preserving split:
// grid 512 blocks x 256 threads; block owns 32 s-values.
// Phase A: thread group g (= tid>>5, 8 groups) computes means for
//   nc in {g, g+8} at its s -> LDS (max 2 nc per thread).
// Phase B: after one __syncthreads, group g computes x_out for its
//   8-b slice, means pulled from LDS into registers once.
// Loss: linear in per-(s,nc) partials -> block shfl/LDS reduce + one
//   atomicAdd per block into out[B*CHW+nd] (out pre-zeroed by harness).
__global__ __launch_bounds__(256)
void k_fused_all(const float* __restrict__ xLE, const int* __restrict__ labels,
                 const float* __restrict__ w1, const float* __restrict__ miu,
                 const float* __restrict__ tao, const float* __restrict__ sigmas,
                 const float* __restrict__ Xw, const float* __restrict__ XLEs,
                 const float* __restrict__ weight,
                 float* __restrict__ out /* [B*CHW] xout, then [ND] loss */) {
    const int tid  = threadIdx.x;
    const int lane = tid & 63;
    const int wv   = tid >> 6;                  // 0..3
    const int sl   = tid & (SS - 1);            // 0..31
    const int g    = tid >> 5;                  // 0..7
    const int s    = blockIdx.x * SS + sl;      // [0, CHW)

    const int lab_l = labels[lane];             // B == 64 == wave size

    // ---- per-thread miu values (for its s), once
    float m0r[ND], lsm0[ND], lsm1[ND], lsme[ND];
#pragma unroll
    for (int nd = 0; nd < ND; ++nd) {
        float m0 = miu[nd * FCHW + s];
        float m1 = miu[nd * FCHW + CHW + s];
        m0r[nd]  = m0;
        lsm0[nd] = log_sigmoid(m0);
        lsm1[nd] = log_sigmoid(m1);
        lsme[nd] = log_sigmoid(m1 + EPS);
    }

    float wn[ND], tao2[ND];
    {
        float s1 = 0.0f;
#pragma unroll
        for (int nd = 0; nd < ND; ++nd) { float t = w1[nd]; wn[nd] = t * t; s1 += t * t; }
        float inv_s1 = 1.0f / s1;
#pragma unroll
        for (int nd = 0; nd < ND; ++nd) {
            wn[nd] *= inv_s1;                   // w1n == w2n in the reference
            float tv = tao[nd];
            tao2[nd] = tv * tv;
        }
    }

    __shared__ float lds_mt[NC][SS];
    __shared__ float lds_lnm[NC][SS];
    __shared__ float red[4][ND];

    // ---- phase A: this group's nc's (nc = g, g+8 while < NC)
    float closs[ND] = {0.0f, 0.0f, 0.0f, 0.0f};
    for (int nc = g; nc < NC; nc += NG) {
        unsigned long long mm = __ballot(lab_l == nc);
        int cint = __popcll(mm);
        float bin0 = XLEs[nc * FCHW + s];
        float bin1 = XLEs[nc * FCHW + CHW + s];
        while (mm) {
            int b = __builtin_ctzll(mm);
            mm &= mm - 1;
            bin0 += xLE[b * FCHW + s];
            bin1 += xLE[b * FCHW + CHW + s];
        }
        float cnt = Xw[nc] + (float)cint;
        float inv_cnt = 1.0f / cnt;
        float xb1 = bin1 * inv_cnt;
        float ls0  = log_sigmoid(bin0 * inv_cnt);
        float ls1v = log_sigmoid(xb1);
        float ls1e = log_sigmoid(xb1 + EPS);
        float sg   = sigmas[nc];
        float sig2 = sg * sg;

        float theta = 0.0f, magm = 0.0f;
#pragma unroll
        for (int nd = 0; nd < ND; ++nd) {
            float d0 = ls0  - lsm0[nd];
            float d1 = ls1v - lsm1[nd];
            float ps = d0 * d0 + d1 * d1;
            float denom = 1.0f / (sig2 + tao2[nd]);
            float rt = tao2[nd] * denom;
            float rs = sig2 * denom;
            theta += (xb1 * rt + m0r[nd] * rs) * wn[nd];
            magm  += expf((rt * ls1e + rs * lsme[nd]) * wn[nd]);
            closs[nd] += (sig2 * denom) * (sig2 * denom) * ps;   // term1*sig2*ps
        }
        lds_mt[nc][sl]  = theta;
        lds_lnm[nc][sl] = logf(magm + EPS);
    }

    // ---- loss: wave-level reduce, then block partial
#pragma unroll
    for (int nd = 0; nd < ND; ++nd) {
        float v = closs[nd];
        for (int off = 32; off > 0; off >>= 1)
            v += __shfl_down(v, off, 64);
        closs[nd] = v;
    }
    if (lane == 0) {
#pragma unroll
        for (int nd = 0; nd < ND; ++nd) red[wv][nd] = closs[nd];
    }

    // constant term (independent of s): wave 0 of block 0 (whole-wave ballots)
    if (blockIdx.x == 0 && wv == 0) {
        float cnts[NC];
#pragma unroll
        for (int c = 0; c < NC; ++c)
            cnts[c] = (float)__popcll(__ballot(lab_l == c));
        if (lane < ND) {
            int nd = lane;
            float t2v  = tao2[nd];
            float tao4 = t2v * t2v;
            float acc = 0.0f;
#pragma unroll
            for (int c = 0; c < NC; ++c) {
                float sg   = sigmas[c];
                float sig2 = sg * sg;
                float cnt  = Xw[c] + cnts[c];
                float denom = 1.0f / (sig2 + t2v);
                float t1 = sig2 * denom * denom;
                float t3 = 2.0f * (float)CHW * (tao4 - sig2 * sig2) / cnt;
                acc += t1 * t3;
            }
            atomicAdd(&out[B * CHW + nd], acc * (1.0f / (float)NC));
        }
    }

    __syncthreads();   // publishes lds_mt/lds_lnm and red

    if (tid < ND) {
        int nd = tid;
        float v = red[0][nd] + red[1][nd] + red[2][nd] + red[3][nd];
        atomicAdd(&out[B * CHW + nd], v * (1.0f / (float)NC));
    }

    // ---- phase B: x_out for this group's 8-b slice, means from registers
    float mtr[NC], lnr[NC];
#pragma unroll
    for (int c = 0; c < NC; ++c) {
        mtr[c] = lds_mt[c][sl];
        lnr[c] = lds_lnm[c][sl];
    }
    float wv0 = weight[0], wv1 = weight[1];
    float w0 = wv0 * wv0, w1s = wv1 * wv1;
    const int b0 = g * (B / NG);               // 8 b's per group
#pragma unroll
    for (int bi = 0; bi < B / NG; ++bi) {
        int b = b0 + bi;
        float x0 = xLE[b * FCHW + s];
        float x1 = xLE[b * FCHW + CHW + s];
        float lnx = logf(x1);
        float best = INFINITY;
#pragma unroll
        for (int c = 0; c < NC; ++c) {
            float d = w0 * fabsf(x0 - mtr[c]) + w1s * fabsf(lnx - lnr[c]);
            best = fminf(best, d);
        }
        out[b * CHW + s] = best;
    }
}

extern "C" void kernel_launch(void* const* d_in, const int* in_sizes, int n_in,
                              void* d_out, int out_size, void* d_ws, size_t ws_size,
                              hipStream_t stream) {
    const float* xLE    = (const float*)d_in[0];
    const int*   labels = (const int*)  d_in[1];
    const float* w1     = (const float*)d_in[2];
    // d_in[3] (w2) is unused: the reference computes w2n from w1.
    const float* miu    = (const float*)d_in[4];
    const float* tao    = (const float*)d_in[5];
    const float* weight = (const float*)d_in[6];
    const float* sigmas = (const float*)d_in[7];
    const float* XLEs   = (const float*)d_in[8];
    const float* Xw     = (const float*)d_in[9];

    float* out = (float*)d_out;   // x_out [B*CHW] then loss [ND]; pre-zeroed by harness

    k_fused_all<<<CHW / SS, 256, 0, stream>>>(
        xLE, labels, w1, miu, tao, sigmas, Xw, XLEs, weight, out);
}